// Round 6
// baseline (77.405 us; speedup 1.0000x reference)
//
#include <hip/hip_runtime.h>
#include <hip/hip_bf16.h>

typedef int   i32x4  __attribute__((ext_vector_type(4)));
typedef int   i32x8  __attribute__((ext_vector_type(8)));
typedef float f32x16 __attribute__((ext_vector_type(16)));

#define BB 2048   // batch dim == GEMM K (1 byte/elem in fp8)
#define NN 4096   // spots dim == GEMM M and N
#define NT 16     // K tiles of 128
// global tiled layout: [row-block rb (32)][kt (16)][chunk (8)][row-in-block (128)] x 16B
// -> tile (rb,kt) is a contiguous 16KB block; LDS buffer is a verbatim copy.

#define SQT_OFF ((size_t)0)
#define MT_OFF  ((size_t)16*1024*1024)
#define SCAL_OFF ((size_t)32*1024*1024)
#define PART_OFF (SCAL_OFF + 1024)
#define PART2_OFF (PART_OFF + 16384)
#define NBLK_P1 (64*32)   // 2048 pass1 blocks
#define NBLK_G  1024      // gemm blocks (32x32 tiles of 128^2)

// exact f32 -> e4m3fn RNE for f >= 0
__device__ __forceinline__ unsigned f32_to_e4m3(float f) {
  if (f >= 448.0f) return 0x7eu;
  if (f < 0.015625f) return (unsigned)(int)rintf(f * 512.0f);
  unsigned u = __float_as_uint(f);
  unsigned r = u + 0x7ffffu + ((u >> 20) & 1u);
  int e = (int)((r >> 23) & 0xff) - 127;
  return ((unsigned)(e + 7) << 3) | ((r >> 20) & 7u);
}

// ---------------- kernel 0: zero accumulators + detect mask dtype ----------------
__global__ void k_detect_zero(const unsigned char* __restrict__ mask,
                              float* __restrict__ scal, int* __restrict__ modep) {
  int lane = threadIdx.x;
  if (lane < 4) scal[lane] = 0.0f;
  bool h3f = false, oddnz = false;
  for (int i = 0; i < 64; ++i) {
    int idx = lane * 64 + i;
    unsigned char v = mask[idx];
    h3f |= (v == 0x3f);
    oddnz |= (((idx & 3) != 0) && (v != 0));
  }
  int mode = __any((int)h3f) ? 2 : (__any((int)oddnz) ? 0 : 1); // 0=u8,1=i32,2=f32
  if (lane == 0) *modep = mode;
}

// ---------------- kernel 1: sq + masked sums + transposed fp8 (tiled k-major) ----
struct P1Acc { float s1, cnt; };

template<int MODE>
__device__ __forceinline__ P1Acc p1_load_phase(
    const float* __restrict__ yhat, const float* __restrict__ y,
    const void* __restrict__ maskraw, unsigned short (*tile)[66],
    int b0, int n0, int brw, int nq)
{
  float4 yv[4], hv[4];
  float mv[4][4];
  #pragma unroll
  for (int rr = 0; rr < 4; ++rr) {
    int brow = brw + rr * 16;
    size_t idx = (size_t)(b0 + brow) * NN + n0 + nq;
    yv[rr] = *(const float4*)(y + idx);
    hv[rr] = *(const float4*)(yhat + idx);
    if (MODE == 0) {
      uchar4 t = *(const uchar4*)((const unsigned char*)maskraw + idx);
      mv[rr][0] = (float)t.x; mv[rr][1] = (float)t.y;
      mv[rr][2] = (float)t.z; mv[rr][3] = (float)t.w;
    } else if (MODE == 1) {
      int4 t = *(const int4*)((const int*)maskraw + idx);
      mv[rr][0] = (t.x != 0) ? 1.f : 0.f; mv[rr][1] = (t.y != 0) ? 1.f : 0.f;
      mv[rr][2] = (t.z != 0) ? 1.f : 0.f; mv[rr][3] = (t.w != 0) ? 1.f : 0.f;
    } else {
      float4 t = *(const float4*)((const float*)maskraw + idx);
      mv[rr][0] = (t.x != 0.f) ? 1.f : 0.f; mv[rr][1] = (t.y != 0.f) ? 1.f : 0.f;
      mv[rr][2] = (t.z != 0.f) ? 1.f : 0.f; mv[rr][3] = (t.w != 0.f) ? 1.f : 0.f;
    }
  }
  float s1 = 0.f, cnt = 0.f;
  #pragma unroll
  for (int rr = 0; rr < 4; ++rr) {
    int brow = brw + rr * 16;
    float d0 = yv[rr].x - hv[rr].x, d1 = yv[rr].y - hv[rr].y;
    float d2 = yv[rr].z - hv[rr].z, d3 = yv[rr].w - hv[rr].w;
    float sq[4] = { d0*d0, d1*d1, d2*d2, d3*d3 };
    unsigned t0 = f32_to_e4m3(sq[0]) | (mv[rr][0] != 0.f ? 0x3800u : 0u);
    unsigned t1 = f32_to_e4m3(sq[1]) | (mv[rr][1] != 0.f ? 0x3800u : 0u);
    unsigned t2 = f32_to_e4m3(sq[2]) | (mv[rr][2] != 0.f ? 0x3800u : 0u);
    unsigned t3 = f32_to_e4m3(sq[3]) | (mv[rr][3] != 0.f ? 0x3800u : 0u);
    *(uint2*)(&tile[brow][nq]) = make_uint2(t0 | (t1 << 16), t2 | (t3 << 16));
    s1 += sq[0]*mv[rr][0] + sq[1]*mv[rr][1] + sq[2]*mv[rr][2] + sq[3]*mv[rr][3];
    cnt += mv[rr][0] + mv[rr][1] + mv[rr][2] + mv[rr][3];
  }
  return { s1, cnt };
}

__global__ __launch_bounds__(256, 2) void k_pass1(
    const float* __restrict__ yhat, const float* __restrict__ y,
    const void* __restrict__ maskraw,
    unsigned char* __restrict__ SQT, unsigned char* __restrict__ MT,
    float2* __restrict__ part, const int* __restrict__ modep)
{
  __shared__ unsigned short tile[64][66];  // [b][n]: lo8 = sq e4m3, hi8 = mask e4m3
  __shared__ float red[8];
  const int mode = *modep;
  const int tid = threadIdx.x;
  const int n0 = blockIdx.x * 64;
  const int b0 = blockIdx.y * 64;
  const int nq = (tid & 15) * 4;
  const int brw = tid >> 4;
  P1Acc a;
  if (mode == 0)      a = p1_load_phase<0>(yhat, y, maskraw, tile, b0, n0, brw, nq);
  else if (mode == 1) a = p1_load_phase<1>(yhat, y, maskraw, tile, b0, n0, brw, nq);
  else                a = p1_load_phase<2>(yhat, y, maskraw, tile, b0, n0, brw, nq);
  __syncthreads();
  // store phase: 16B chunk = 16 consecutive b of one n-row, at tiled k-major addr
  {
    int nrow = tid >> 2;              // 0..63
    int cb   = tid & 3;               // which 16-byte b-chunk
    int grow = n0 + nrow;
    unsigned us[4], um[4];
    #pragma unroll
    for (int q = 0; q < 4; ++q) {
      unsigned v0 = tile[cb*16 + q*4 + 0][nrow];
      unsigned v1 = tile[cb*16 + q*4 + 1][nrow];
      unsigned v2 = tile[cb*16 + q*4 + 2][nrow];
      unsigned v3 = tile[cb*16 + q*4 + 3][nrow];
      us[q] = (v0 & 0xffu) | ((v1 & 0xffu) << 8) | ((v2 & 0xffu) << 16) | ((v3 & 0xffu) << 24);
      um[q] = (v0 >> 8) | ((v1 >> 8) << 8) | ((v2 >> 8) << 16) | ((v3 >> 8) << 24);
    }
    int gb = b0 + cb * 16;
    size_t off = (size_t)(grow >> 7) * 262144 + (size_t)(gb >> 7) * 16384
               + (size_t)((gb >> 4) & 7) * 2048 + (size_t)(grow & 127) * 16;
    *(uint4*)(SQT + off) = make_uint4(us[0], us[1], us[2], us[3]);
    *(uint4*)(MT  + off) = make_uint4(um[0], um[1], um[2], um[3]);
  }
  float s1 = a.s1, cnt = a.cnt;
  #pragma unroll
  for (int off = 32; off >= 1; off >>= 1) {
    s1  += __shfl_down(s1,  off, 64);
    cnt += __shfl_down(cnt, off, 64);
  }
  int wv = tid >> 6;
  if ((tid & 63) == 0) { red[wv] = s1; red[4 + wv] = cnt; }
  __syncthreads();
  if (tid == 0)
    part[blockIdx.y * gridDim.x + blockIdx.x] =
        make_float2(red[0] + red[1] + red[2] + red[3],
                    red[4] + red[5] + red[6] + red[7]);
}

// ---------------- kernel 2: MX-fp8 GEMM 128x128, BK=128, 8 waves, 2 blocks/CU ----
__global__ __launch_bounds__(512, 4) void k_gemm(
    const unsigned char* __restrict__ MT,
    const unsigned char* __restrict__ SQT,
    const float* __restrict__ W,
    float* __restrict__ part2)
{
  extern __shared__ char lds[];   // A: [2][16KB] @0 ; B: [2][16KB] @32768
  const int tid = threadIdx.x;
  const int lane = tid & 63;
  const int wave = tid >> 6;       // 0..7
  const int wmB = (wave >> 1) * 32;   // 4 M-waves
  const int wnB = (wave & 1) * 64;    // 2 N-waves
  const int l31 = lane & 31;
  const int lch2 = (lane >> 5) * 2;   // chunk-pair select within k-half

  // XCD-aware bijective swizzle (1024 % 8 == 0)
  int bid = blockIdx.x;
  int swz = (bid & 7) * 128 + (bid >> 3);
  const int nb = swz & 31, ib = swz >> 5;
  const int n0 = nb * 128, i0 = ib * 128;

  const unsigned char* aSrc = MT  + (size_t)ib * 262144;
  const unsigned char* bSrc = SQT + (size_t)nb * 262144;
  const int tid16 = tid * 16;

#define STG_A(c, kt) \
  { __builtin_amdgcn_global_load_lds( \
      (const __attribute__((address_space(1))) unsigned int*)(aSrc + (size_t)(kt)*16384 + tid16), \
      (__attribute__((address_space(3))) unsigned int*)(lds + (c)*16384 + tid16), 16, 0, 0); \
    __builtin_amdgcn_global_load_lds( \
      (const __attribute__((address_space(1))) unsigned int*)(aSrc + (size_t)(kt)*16384 + 8192 + tid16), \
      (__attribute__((address_space(3))) unsigned int*)(lds + (c)*16384 + 8192 + tid16), 16, 0, 0); }
#define STG_B(c, kt) \
  { __builtin_amdgcn_global_load_lds( \
      (const __attribute__((address_space(1))) unsigned int*)(bSrc + (size_t)(kt)*16384 + tid16), \
      (__attribute__((address_space(3))) unsigned int*)(lds + 32768 + (c)*16384 + tid16), 16, 0, 0); \
    __builtin_amdgcn_global_load_lds( \
      (const __attribute__((address_space(1))) unsigned int*)(bSrc + (size_t)(kt)*16384 + 8192 + tid16), \
      (__attribute__((address_space(3))) unsigned int*)(lds + 32768 + (c)*16384 + 8192 + tid16), 16, 0, 0); }

  // k-major fragment reads: lanes 0-31 contiguous 512B -> conflict-free
#define RD_A(dst, c, kh) { \
    const char* p = lds + (c)*16384 + ((kh)*4 + lch2)*2048 + (wmB + l31)*16; \
    i32x4 lo = *(const i32x4*)p; \
    i32x4 hi = *(const i32x4*)(p + 2048); \
    dst = __builtin_shufflevector(lo, hi, 0, 1, 2, 3, 4, 5, 6, 7); }
#define RD_B(dst, c, kh) \
  _Pragma("unroll") for (int ng = 0; ng < 2; ++ng) { \
    const char* p = lds + 32768 + (c)*16384 + ((kh)*4 + lch2)*2048 + (wnB + ng*32 + l31)*16; \
    i32x4 lo = *(const i32x4*)p; \
    i32x4 hi = *(const i32x4*)(p + 2048); \
    dst[ng] = __builtin_shufflevector(lo, hi, 0, 1, 2, 3, 4, 5, 6, 7); }
#define MFMA_H(AS, BS) \
  __builtin_amdgcn_s_setprio(1); \
  _Pragma("unroll") for (int ng = 0; ng < 2; ++ng) \
    acc[ng] = __builtin_amdgcn_mfma_scale_f32_32x32x64_f8f6f4( \
        AS, BS[ng], acc[ng], 0, 0, 0, 0x7f7f7f7f, 0, 0x7f7f7f7f); \
  __builtin_amdgcn_s_setprio(0); \
  __builtin_amdgcn_s_barrier(); \
  __builtin_amdgcn_sched_barrier(0)

  i32x8 a0, a1, b0v[2], b1v[2];
  f32x16 acc[2] = {};

  // prologue: tile0 -> buf0, tile1 -> buf1 (8 insts); wait tile0; preload khalf0(0)
  STG_A(0, 0); STG_B(0, 0);
  STG_A(1, 1); STG_B(1, 1);
  asm volatile("s_waitcnt vmcnt(4)" ::: "memory");
  __builtin_amdgcn_s_barrier();
  __builtin_amdgcn_sched_barrier(0);
  RD_A(a0, 0, 0);
  RD_B(b0v, 0, 0);

  for (int t = 0; t < NT; ++t) {
    const int c = t & 1, cn = c ^ 1;
    const bool st = (t + 2) < NT;
    const bool rn = (t + 1) < NT;

    // ---- P1: read khalf1(t) from buf c; MFMA khalf0 (prev regs); barrier
    RD_A(a1, c, 1);
    RD_B(b1v, c, 1);
    MFMA_H(a0, b0v);

    // ---- P2: stage tile t+2 -> buf c; counted vmcnt (tile t+1 landed);
    //          read khalf0(t+1) from buf cn; MFMA khalf1; barrier
    if (st) {
      STG_A(c, t + 2); STG_B(c, t + 2);
      asm volatile("s_waitcnt vmcnt(4)" ::: "memory");
    } else {
      asm volatile("s_waitcnt vmcnt(0)" ::: "memory");
    }
    if (rn) { RD_A(a0, cn, 0); RD_B(b0v, cn, 0); }
    MFMA_H(a1, b1v);
  }
#undef STG_A
#undef STG_B
#undef RD_A
#undef RD_B
#undef MFMA_H

  // epilogue: dot T-tile with W; 32x32 C/D: col=lane&31, row=(reg&3)+8*(reg>>2)+4*(lane>>5)
  float local = 0.0f;
  {
    int rbase = i0 + wmB + (lane >> 5) * 4;
    #pragma unroll
    for (int ng = 0; ng < 2; ++ng) {
      int nn = n0 + wnB + ng * 32 + l31;
      const float* wp = W + (size_t)rbase * NN + nn;
      #pragma unroll
      for (int reg = 0; reg < 16; ++reg) {
        int roff = (reg & 3) + 8 * (reg >> 2);
        local += acc[ng][reg] * wp[(size_t)roff * NN];
      }
    }
  }
  #pragma unroll
  for (int off = 32; off >= 1; off >>= 1)
    local += __shfl_down(local, off, 64);
  float* wpart = (float*)lds;
  if (lane == 0) wpart[wave] = local;
  __builtin_amdgcn_s_barrier();
  if (tid == 0) {
    float s = 0.f;
    #pragma unroll
    for (int i = 0; i < 8; ++i) s += wpart[i];
    part2[blockIdx.x] = s;
  }
}

// ---------------- kernel 3: finalize (reduce partials + sqrt) ----------------
__global__ __launch_bounds__(256) void k_finalize(
    const float2* __restrict__ part, const float* __restrict__ part2,
    float* __restrict__ out)
{
  __shared__ float rs[4], rc[4];
  float s1 = 0.f, cnt = 0.f;
  for (int i = threadIdx.x; i < NBLK_P1; i += 256) {
    float2 p = part[i];
    s1 += p.x; cnt += p.y;
  }
  for (int i = threadIdx.x; i < NBLK_G; i += 256)
    s1 += part2[i];
  #pragma unroll
  for (int off = 32; off >= 1; off >>= 1) {
    s1  += __shfl_down(s1,  off, 64);
    cnt += __shfl_down(cnt, off, 64);
  }
  int wv = threadIdx.x >> 6;
  if ((threadIdx.x & 63) == 0) { rs[wv] = s1; rc[wv] = cnt; }
  __syncthreads();
  if (threadIdx.x == 0) {
    float S = rs[0] + rs[1] + rs[2] + rs[3];
    float C = rc[0] + rc[1] + rc[2] + rc[3];
    out[0] = sqrtf(S / C + 1e-6f);
  }
}

__global__ void k_sentinel(float* out) { out[0] = 1.2345e8f; }  // ws too small marker

extern "C" void kernel_launch(void* const* d_in, const int* in_sizes, int n_in,
                              void* d_out, int out_size, void* d_ws, size_t ws_size,
                              hipStream_t stream) {
  const float* yhat = (const float*)d_in[0];
  const float* y    = (const float*)d_in[1];
  const void*  mask = d_in[2];
  const float* W    = (const float*)d_in[3];
  float* out = (float*)d_out;

  const size_t need = PART2_OFF + (size_t)NBLK_G * 4;
  if (ws_size < need) { k_sentinel<<<1, 1, 0, stream>>>(out); return; }

  char* ws = (char*)d_ws;
  unsigned char* SQT = (unsigned char*)(ws + SQT_OFF);  // [32][16][8][128]x16B tiled fp8
  unsigned char* MTp = (unsigned char*)(ws + MT_OFF);
  float* scal = (float*)(ws + SCAL_OFF);
  int* modep  = (int*)(ws + SCAL_OFF + 16);
  float2* part = (float2*)(ws + PART_OFF);
  float* part2 = (float*)(ws + PART2_OFF);

  (void)hipFuncSetAttribute((const void*)k_gemm,
                            hipFuncAttributeMaxDynamicSharedMemorySize, 65536);

  k_detect_zero<<<1, 64, 0, stream>>>((const unsigned char*)mask, scal, modep);
  k_pass1<<<dim3(NN/64, BB/64), 256, 0, stream>>>(yhat, y, mask, SQT, MTp, part, modep);
  k_gemm<<<NBLK_G, 512, 65536, stream>>>(MTp, SQT, W, part2);
  k_finalize<<<1, 256, 0, stream>>>(part, part2, out);
}

// Round 7
// 59.018 us; speedup vs baseline: 1.3116x; 1.3116x over previous
//
#include <hip/hip_runtime.h>
#include <hip/hip_bf16.h>

typedef int   i32x4  __attribute__((ext_vector_type(4)));
typedef int   i32x8  __attribute__((ext_vector_type(8)));
typedef float f32x16 __attribute__((ext_vector_type(16)));

#define BB 2048   // batch dim == GEMM K (1 byte/elem in fp8)
#define NN 4096   // spots dim == GEMM M and N
#define NT 16     // K tiles of 128
// global tiled layout: [rb (32 row-blocks of 128)][kt (16)][chunk (8)][row (128)] x 16B
// -> (rb,kt) is a contiguous 16KB block; LDS staging is a verbatim copy.

#define SQT_OFF ((size_t)0)
#define MT_OFF  ((size_t)16*1024*1024)
#define SCAL_OFF ((size_t)32*1024*1024)
#define PART_OFF (SCAL_OFF + 1024)
#define PART2_OFF (PART_OFF + 16384)
#define NBLK_P1 (64*32)   // 2048 pass1 blocks
#define NBLK_G  256       // gemm blocks (16x16 tiles of 256^2)

// exact f32 -> e4m3fn RNE for f >= 0
__device__ __forceinline__ unsigned f32_to_e4m3(float f) {
  if (f >= 448.0f) return 0x7eu;
  if (f < 0.015625f) return (unsigned)(int)rintf(f * 512.0f);
  unsigned u = __float_as_uint(f);
  unsigned r = u + 0x7ffffu + ((u >> 20) & 1u);
  int e = (int)((r >> 23) & 0xff) - 127;
  return ((unsigned)(e + 7) << 3) | ((r >> 20) & 7u);
}

// ---------------- kernel 1: sq + masked sums + fp8 k-major tiles (+inline mode) --
struct P1Acc { float s1, cnt; };

template<int MODE>
__device__ __forceinline__ P1Acc p1_load_phase(
    const float* __restrict__ yhat, const float* __restrict__ y,
    const void* __restrict__ maskraw, unsigned short (*tile)[66],
    int b0, int n0, int brw, int nq)
{
  float4 yv[4], hv[4];
  float mv[4][4];
  #pragma unroll
  for (int rr = 0; rr < 4; ++rr) {
    int brow = brw + rr * 16;
    size_t idx = (size_t)(b0 + brow) * NN + n0 + nq;
    yv[rr] = *(const float4*)(y + idx);
    hv[rr] = *(const float4*)(yhat + idx);
    if (MODE == 0) {
      uchar4 t = *(const uchar4*)((const unsigned char*)maskraw + idx);
      mv[rr][0] = (float)t.x; mv[rr][1] = (float)t.y;
      mv[rr][2] = (float)t.z; mv[rr][3] = (float)t.w;
    } else if (MODE == 1) {
      int4 t = *(const int4*)((const int*)maskraw + idx);
      mv[rr][0] = (t.x != 0) ? 1.f : 0.f; mv[rr][1] = (t.y != 0) ? 1.f : 0.f;
      mv[rr][2] = (t.z != 0) ? 1.f : 0.f; mv[rr][3] = (t.w != 0) ? 1.f : 0.f;
    } else {
      float4 t = *(const float4*)((const float*)maskraw + idx);
      mv[rr][0] = (t.x != 0.f) ? 1.f : 0.f; mv[rr][1] = (t.y != 0.f) ? 1.f : 0.f;
      mv[rr][2] = (t.z != 0.f) ? 1.f : 0.f; mv[rr][3] = (t.w != 0.f) ? 1.f : 0.f;
    }
  }
  float s1 = 0.f, cnt = 0.f;
  #pragma unroll
  for (int rr = 0; rr < 4; ++rr) {
    int brow = brw + rr * 16;
    float d0 = yv[rr].x - hv[rr].x, d1 = yv[rr].y - hv[rr].y;
    float d2 = yv[rr].z - hv[rr].z, d3 = yv[rr].w - hv[rr].w;
    float sq[4] = { d0*d0, d1*d1, d2*d2, d3*d3 };
    unsigned t0 = f32_to_e4m3(sq[0]) | (mv[rr][0] != 0.f ? 0x3800u : 0u);
    unsigned t1 = f32_to_e4m3(sq[1]) | (mv[rr][1] != 0.f ? 0x3800u : 0u);
    unsigned t2 = f32_to_e4m3(sq[2]) | (mv[rr][2] != 0.f ? 0x3800u : 0u);
    unsigned t3 = f32_to_e4m3(sq[3]) | (mv[rr][3] != 0.f ? 0x3800u : 0u);
    *(uint2*)(&tile[brow][nq]) = make_uint2(t0 | (t1 << 16), t2 | (t3 << 16));
    s1 += sq[0]*mv[rr][0] + sq[1]*mv[rr][1] + sq[2]*mv[rr][2] + sq[3]*mv[rr][3];
    cnt += mv[rr][0] + mv[rr][1] + mv[rr][2] + mv[rr][3];
  }
  return { s1, cnt };
}

__global__ __launch_bounds__(256, 2) void k_pass1(
    const float* __restrict__ yhat, const float* __restrict__ y,
    const void* __restrict__ maskraw,
    unsigned char* __restrict__ SQT, unsigned char* __restrict__ MT,
    float2* __restrict__ part)
{
  __shared__ unsigned short tile[64][66];  // [b][n]: lo8 = sq e4m3, hi8 = mask e4m3
  __shared__ float red[8];
  __shared__ unsigned mflag;
  const int tid = threadIdx.x;
  const int lane = tid & 63;
  // inline mask-dtype detection on first 4KB (identical logic to old k_detect_zero)
  if (tid == 0) mflag = 0;
  __syncthreads();
  {
    uint4 mb = *(const uint4*)((const unsigned char*)maskraw + tid * 16);
    unsigned f = 0;
    unsigned ws[4] = { mb.x, mb.y, mb.z, mb.w };
    #pragma unroll
    for (int q = 0; q < 4; ++q) {
      unsigned w = ws[q];
      bool h3f = ((w & 0xffu) == 0x3fu) | (((w >> 8) & 0xffu) == 0x3fu) |
                 (((w >> 16) & 0xffu) == 0x3fu) | ((w >> 24) == 0x3fu);
      f |= h3f ? 1u : 0u;
      f |= ((w & 0xffffff00u) != 0u) ? 2u : 0u;   // nonzero byte at offset%4 != 0
    }
    bool a1 = __any((int)(f & 1)), a2 = __any((int)(f & 2));
    if (lane == 0) {
      unsigned g = (a1 ? 1u : 0u) | (a2 ? 2u : 0u);
      if (g) atomicOr(&mflag, g);
    }
  }
  __syncthreads();
  const unsigned mf = mflag;
  const int mode = (mf & 1) ? 2 : ((mf & 2) ? 0 : 1);  // 0=u8, 1=i32, 2=f32

  const int n0 = blockIdx.x * 64;
  const int b0 = blockIdx.y * 64;
  const int nq = (tid & 15) * 4;
  const int brw = tid >> 4;
  P1Acc a;
  if (mode == 0)      a = p1_load_phase<0>(yhat, y, maskraw, tile, b0, n0, brw, nq);
  else if (mode == 1) a = p1_load_phase<1>(yhat, y, maskraw, tile, b0, n0, brw, nq);
  else                a = p1_load_phase<2>(yhat, y, maskraw, tile, b0, n0, brw, nq);
  __syncthreads();
  // store phase: 16B chunk = 16 consecutive b of one n-row, at tiled k-major addr
  {
    int nrow = tid >> 2;              // 0..63
    int cb   = tid & 3;               // which 16-byte b-chunk
    int grow = n0 + nrow;
    unsigned us[4], um[4];
    #pragma unroll
    for (int q = 0; q < 4; ++q) {
      unsigned v0 = tile[cb*16 + q*4 + 0][nrow];
      unsigned v1 = tile[cb*16 + q*4 + 1][nrow];
      unsigned v2 = tile[cb*16 + q*4 + 2][nrow];
      unsigned v3 = tile[cb*16 + q*4 + 3][nrow];
      us[q] = (v0 & 0xffu) | ((v1 & 0xffu) << 8) | ((v2 & 0xffu) << 16) | ((v3 & 0xffu) << 24);
      um[q] = (v0 >> 8) | ((v1 >> 8) << 8) | ((v2 >> 8) << 16) | ((v3 >> 8) << 24);
    }
    int gb = b0 + cb * 16;
    size_t off = (size_t)(grow >> 7) * 262144 + (size_t)(gb >> 7) * 16384
               + (size_t)((gb >> 4) & 7) * 2048 + (size_t)(grow & 127) * 16;
    *(uint4*)(SQT + off) = make_uint4(us[0], us[1], us[2], us[3]);
    *(uint4*)(MT  + off) = make_uint4(um[0], um[1], um[2], um[3]);
  }
  float s1 = a.s1, cnt = a.cnt;
  #pragma unroll
  for (int off = 32; off >= 1; off >>= 1) {
    s1  += __shfl_down(s1,  off, 64);
    cnt += __shfl_down(cnt, off, 64);
  }
  int wv = tid >> 6;
  if ((tid & 63) == 0) { red[wv] = s1; red[4 + wv] = cnt; }
  __syncthreads();
  if (tid == 0)
    part[blockIdx.y * gridDim.x + blockIdx.x] =
        make_float2(red[0] + red[1] + red[2] + red[3],
                    red[4] + red[5] + red[6] + red[7]);
}

// -------- kernel 2: MX-fp8 GEMM 256x256, BK=128, 8 waves, 4 phases/K-tile --------
__global__ __launch_bounds__(512, 2) void k_gemm(
    const unsigned char* __restrict__ MT,
    const unsigned char* __restrict__ SQT,
    const float* __restrict__ W,
    float* __restrict__ part2)
{
  extern __shared__ char lds[];   // A: [2][32KB] @0 ; B: [2][32KB] @65536
  const int tid = threadIdx.x;
  const int lane = tid & 63;
  const int wave = tid >> 6;          // 0..7
  const int wm  = wave >> 2;          // 0..1 : wave owns 128 M rows
  const int wmB = wm * 128;
  const int wnB = (wave & 3) * 64;    // wave owns 64 N cols
  const int l31 = lane & 31;
  const int lch2 = (lane >> 5) * 2;   // chunk-pair select (lane-half k split)

  // XCD-aware bijective swizzle (256 % 8 == 0)
  int bid = blockIdx.x;
  int swz = (bid & 7) * 32 + (bid >> 3);
  const int nb = swz & 15, ib = swz >> 4;
  const int n0 = nb * 256, i0 = ib * 256;

  const unsigned char* aSrc = MT  + (size_t)ib * 524288;  // 2 rb-blocks
  const unsigned char* bSrc = SQT + (size_t)nb * 524288;
  const int tid16 = tid * 16;

  // stage one K-tile (32KB = 4 insts of 8KB); LDS layout [rb(2)][kh(2)][chunk4][row128]x16B
#define STG_A(c, kt) \
  _Pragma("unroll") for (int j = 0; j < 4; ++j) { \
    __builtin_amdgcn_global_load_lds( \
      (const __attribute__((address_space(1))) unsigned int*)( \
          aSrc + (size_t)(j >> 1) * 262144 + (size_t)(kt) * 16384 + (j & 1) * 8192 + tid16), \
      (__attribute__((address_space(3))) unsigned int*)(lds + (c) * 32768 + j * 8192 + tid16), \
      16, 0, 0); }
#define STG_B(c, kt) \
  _Pragma("unroll") for (int j = 0; j < 4; ++j) { \
    __builtin_amdgcn_global_load_lds( \
      (const __attribute__((address_space(1))) unsigned int*)( \
          bSrc + (size_t)(j >> 1) * 262144 + (size_t)(kt) * 16384 + (j & 1) * 8192 + tid16), \
      (__attribute__((address_space(3))) unsigned int*)(lds + 65536 + (c) * 32768 + j * 8192 + tid16), \
      16, 0, 0); }

  // k-major fragment reads: lanes 0-31 contiguous 512B -> conflict-free
#define RD_A_H(dst, c, kh, mgb) \
  _Pragma("unroll") for (int mg = (mgb); mg < (mgb) + 2; ++mg) { \
    const char* p = lds + (c)*32768 + wm*16384 + (kh)*8192 + lch2*2048 + (mg*32 + l31)*16; \
    i32x4 lo = *(const i32x4*)p; \
    i32x4 hi = *(const i32x4*)(p + 2048); \
    dst[mg] = __builtin_shufflevector(lo, hi, 0, 1, 2, 3, 4, 5, 6, 7); }
#define RD_B(dst, c, kh) \
  _Pragma("unroll") for (int ng = 0; ng < 2; ++ng) { \
    int rowg = wnB + ng * 32; \
    const char* p = lds + 65536 + (c)*32768 + (rowg >> 7)*16384 + (kh)*8192 \
                  + lch2*2048 + ((rowg & 127) + l31)*16; \
    i32x4 lo = *(const i32x4*)p; \
    i32x4 hi = *(const i32x4*)(p + 2048); \
    dst[ng] = __builtin_shufflevector(lo, hi, 0, 1, 2, 3, 4, 5, 6, 7); }
#define MFMA2(AF, BF, mgb) \
  __builtin_amdgcn_s_setprio(1); \
  _Pragma("unroll") for (int mg = (mgb); mg < (mgb) + 2; ++mg) \
    _Pragma("unroll") for (int ng = 0; ng < 2; ++ng) \
      acc[mg][ng] = __builtin_amdgcn_mfma_scale_f32_32x32x64_f8f6f4( \
          AF[mg], BF[ng], acc[mg][ng], 0, 0, 0, 0x7f7f7f7f, 0, 0x7f7f7f7f); \
  __builtin_amdgcn_s_setprio(0); \
  __builtin_amdgcn_s_barrier(); \
  __builtin_amdgcn_sched_barrier(0)

  i32x8 a0[4], a1[4], b0v[2], b1v[2];
  f32x16 acc[4][2] = {};

  // prologue: tile0 -> buf0, tile1 -> buf1 (16 insts); wait tile0; preload kh0(0)
  STG_A(0, 0); STG_B(0, 0);
  STG_A(1, 1); STG_B(1, 1);
  asm volatile("s_waitcnt vmcnt(8)" ::: "memory");
  __builtin_amdgcn_s_barrier();
  __builtin_amdgcn_sched_barrier(0);
  RD_A_H(a0, 0, 0, 0); RD_A_H(a0, 0, 0, 2); RD_B(b0v, 0, 0);

  for (int t = 0; t < NT; ++t) {
    const int c = t & 1, cn = c ^ 1;
    const bool st = (t + 2) < NT;
    const bool rn = (t + 1) < NT;

    // ---- P1a: read kh1 A mg0-1; MFMA kh0 mg0-1
    RD_A_H(a1, c, 1, 0);
    MFMA2(a0, b0v, 0);

    // ---- P1b: read kh1 A mg2-3 + B; MFMA kh0 mg2-3
    RD_A_H(a1, c, 1, 2);
    RD_B(b1v, c, 1);
    MFMA2(a0, b0v, 2);

    // ---- P2a: stage A(t+2) into buf c (A reads of buf c done at P1b barrier); MFMA kh1 mg0-1
    if (st) { STG_A(c, t + 2); }
    MFMA2(a1, b1v, 0);

    // ---- P2b: stage B(t+2); counted vmcnt -> tile t+1 landed; read kh0(t+1); MFMA kh1 mg2-3
    if (st) {
      STG_B(c, t + 2);
      asm volatile("s_waitcnt vmcnt(8)" ::: "memory");
    } else {
      asm volatile("s_waitcnt vmcnt(0)" ::: "memory");
    }
    if (rn) { RD_A_H(a0, cn, 0, 0); RD_A_H(a0, cn, 0, 2); RD_B(b0v, cn, 0); }
    MFMA2(a1, b1v, 2);
  }
#undef STG_A
#undef STG_B
#undef RD_A_H
#undef RD_B
#undef MFMA2

  // epilogue: dot T-tile with W; 32x32 C/D: col=lane&31, row=(reg&3)+8*(reg>>2)+4*(lane>>5)
  float local = 0.0f;
  #pragma unroll
  for (int mg = 0; mg < 4; ++mg) {
    int rbase = i0 + wmB + mg * 32 + (lane >> 5) * 4;
    #pragma unroll
    for (int ng = 0; ng < 2; ++ng) {
      int nn = n0 + wnB + ng * 32 + l31;
      const float* wp = W + (size_t)rbase * NN + nn;
      #pragma unroll
      for (int reg = 0; reg < 16; ++reg) {
        int roff = (reg & 3) + 8 * (reg >> 2);
        local += acc[mg][ng][reg] * wp[(size_t)roff * NN];
      }
    }
  }
  #pragma unroll
  for (int off = 32; off >= 1; off >>= 1)
    local += __shfl_down(local, off, 64);
  float* wpart = (float*)lds;
  if (lane == 0) wpart[wave] = local;
  __builtin_amdgcn_s_barrier();
  if (tid == 0) {
    float s = 0.f;
    #pragma unroll
    for (int i = 0; i < 8; ++i) s += wpart[i];
    part2[blockIdx.x] = s;
  }
}

// ---------------- kernel 3: finalize (reduce partials + sqrt) ----------------
__global__ __launch_bounds__(256) void k_finalize(
    const float2* __restrict__ part, const float* __restrict__ part2,
    float* __restrict__ out)
{
  __shared__ float rs[4], rc[4];
  float s1 = 0.f, cnt = 0.f;
  for (int i = threadIdx.x; i < NBLK_P1; i += 256) {
    float2 p = part[i];
    s1 += p.x; cnt += p.y;
  }
  for (int i = threadIdx.x; i < NBLK_G; i += 256)
    s1 += part2[i];
  #pragma unroll
  for (int off = 32; off >= 1; off >>= 1) {
    s1  += __shfl_down(s1,  off, 64);
    cnt += __shfl_down(cnt, off, 64);
  }
  int wv = threadIdx.x >> 6;
  if ((threadIdx.x & 63) == 0) { rs[wv] = s1; rc[wv] = cnt; }
  __syncthreads();
  if (threadIdx.x == 0) {
    float S = rs[0] + rs[1] + rs[2] + rs[3];
    float C = rc[0] + rc[1] + rc[2] + rc[3];
    out[0] = sqrtf(S / C + 1e-6f);
  }
}

__global__ void k_sentinel(float* out) { out[0] = 1.2345e8f; }  // ws too small marker

extern "C" void kernel_launch(void* const* d_in, const int* in_sizes, int n_in,
                              void* d_out, int out_size, void* d_ws, size_t ws_size,
                              hipStream_t stream) {
  const float* yhat = (const float*)d_in[0];
  const float* y    = (const float*)d_in[1];
  const void*  mask = d_in[2];
  const float* W    = (const float*)d_in[3];
  float* out = (float*)d_out;

  const size_t need = PART2_OFF + (size_t)NBLK_G * 4;
  if (ws_size < need) { k_sentinel<<<1, 1, 0, stream>>>(out); return; }

  char* ws = (char*)d_ws;
  unsigned char* SQT = (unsigned char*)(ws + SQT_OFF);  // [32][16][8][128]x16B tiled fp8
  unsigned char* MTp = (unsigned char*)(ws + MT_OFF);
  float2* part = (float2*)(ws + PART_OFF);
  float* part2 = (float*)(ws + PART2_OFF);

  (void)hipFuncSetAttribute((const void*)k_gemm,
                            hipFuncAttributeMaxDynamicSharedMemorySize, 131072);

  k_pass1<<<dim3(NN/64, BB/64), 256, 0, stream>>>(yhat, y, mask, SQT, MTp, part);
  k_gemm<<<NBLK_G, 512, 131072, stream>>>(MTp, SQT, W, part2);
  k_finalize<<<1, 256, 0, stream>>>(part, part2, out);
}